// Round 7
// baseline (193.590 us; speedup 1.0000x reference)
//
#include <hip/hip_runtime.h>
#include <hip/hip_bf16.h>
#include <math.h>

#define BB 16
#define CC 512
#define NH 8
#define HD 64
#define NN 1024   // H*W
#define THREEC 1536

// Q pre-scale: (1/sqrt(64)) * log2(e)  -> softmax via raw v_exp_f32 (2^x)
#define QSCALE 0.18033688f

typedef __attribute__((ext_vector_type(8))) short bf16x8;
typedef __attribute__((ext_vector_type(4))) float f32x4;
typedef __attribute__((ext_vector_type(16))) float f32x16;

#if __has_builtin(__builtin_amdgcn_exp2f)
#define EXP2F __builtin_amdgcn_exp2f
#else
#define EXP2F exp2f
#endif

// workspace byte offsets
#define XT_OFF 0u           // bf16 x^T [b][n][c]          (16.78 MB)
#define WQ_OFF 16777216u    // bf16 w_qkv [1536][512]      (1.57 MB)
#define WP_OFF 18350080u    // bf16 w_proj [512][512]      (0.52 MB)
#define QB_OFF 18874368u    // bf16 Q (scaled QSCALE) [bh][n][d]
#define KB_OFF 35651584u    // bf16 K [bh][n][d]
#define VT_OFF 52428800u    // bf16 V^T [bh][d][n]
#define AB_OFF 69206016u    // bf16 attn-out [b][n][c]
// end 85983232 (82 MiB)

static __device__ inline unsigned short f2bf(float f) {
  union { float f; unsigned u; } v; v.f = f;
  unsigned r = v.u + 0x7fffu + ((v.u >> 16) & 1u);
  return (unsigned short)(r >> 16);
}

// pack two f32 -> two bf16 in a u32 (lo = a, hi = b)
static __device__ inline unsigned pk2bf(float a, float b) {
#if defined(__AMDGCN__) && __has_builtin(__builtin_amdgcn_cvt_pk_bf16_f32)
  typedef __attribute__((ext_vector_type(2))) __bf16 bfp2;
  union { bfp2 v; unsigned u; } z;
  z.v = __builtin_amdgcn_cvt_pk_bf16_f32(a, b);
  return z.u;
#else
  return (unsigned)f2bf(a) | ((unsigned)f2bf(b) << 16);
#endif
}

static __device__ inline void gld_lds16(const unsigned short* g, unsigned short* l) {
  __builtin_amdgcn_global_load_lds(
      (const __attribute__((address_space(1))) unsigned int*)g,
      (__attribute__((address_space(3))) unsigned int*)l, 16, 0, 0);
}

// ---------------------------------------------------------------------------
// prep_w: convert w_qkv (786432) + w_proj (262144) fp32 -> bf16
// ---------------------------------------------------------------------------
__global__ __launch_bounds__(256) void prep_w(const float* __restrict__ wqkv,
                                              const float* __restrict__ wproj,
                                              unsigned short* __restrict__ dq,
                                              unsigned short* __restrict__ dp) {
  const size_t i8 = ((size_t)blockIdx.x * 256 + threadIdx.x) * 8;
  const float* src;
  unsigned short* dst;
  if (i8 < 786432u) { src = wqkv + i8; dst = dq + i8; }
  else              { src = wproj + (i8 - 786432u); dst = dp + (i8 - 786432u); }
  float4 a = *(const float4*)src;
  float4 b = *(const float4*)(src + 4);
  unsigned short pk[8] = {f2bf(a.x), f2bf(a.y), f2bf(a.z), f2bf(a.w),
                          f2bf(b.x), f2bf(b.y), f2bf(b.z), f2bf(b.w)};
  *(uint4*)dst = *(const uint4*)pk;
}

// ---------------------------------------------------------------------------
// prep_xT: x [b][c][n] fp32 -> xT [b][n][c] bf16. 64x64 LDS tile transpose.
// ---------------------------------------------------------------------------
__global__ __launch_bounds__(256) void prep_xT(const float* __restrict__ x,
                                               unsigned short* __restrict__ xT) {
  const int b  = blockIdx.z;
  const int c0 = blockIdx.y * 64;
  const int n0 = blockIdx.x * 64;
  __shared__ float tile[64][65];
  const int t  = threadIdx.x;
  const int cl = t >> 4, n4 = (t & 15) * 4;
#pragma unroll
  for (int r = 0; r < 4; ++r) {
    float4 v = *(const float4*)&x[((size_t)b * CC + c0 + cl + 16 * r) * NN + n0 + n4];
    *(float4*)&tile[cl + 16 * r][n4] = v;
  }
  __syncthreads();
  const int nl = t >> 4, c4 = (t & 15) * 4;
#pragma unroll
  for (int r = 0; r < 4; ++r) {
    ushort4 p;
    p.x = f2bf(tile[c4 + 0][nl + 16 * r]);
    p.y = f2bf(tile[c4 + 1][nl + 16 * r]);
    p.z = f2bf(tile[c4 + 2][nl + 16 * r]);
    p.w = f2bf(tile[c4 + 3][nl + 16 * r]);
    *(ushort4*)&xT[((size_t)b * NN + n0 + nl + 16 * r) * CC + c0 + c4] = p;
  }
}

// ---------------------------------------------------------------------------
// qkv_mfma: [1536x512] @ [512x1024] per batch, bf16 MFMA, 128x128 tile BK=64.
// ---------------------------------------------------------------------------
__global__ __launch_bounds__(256) void qkv_mfma(const unsigned short* __restrict__ wq,
                                                const unsigned short* __restrict__ xT,
                                                unsigned short* __restrict__ qb,
                                                unsigned short* __restrict__ kb_,
                                                unsigned short* __restrict__ vt) {
  const int b  = blockIdx.z;
  const int o0 = blockIdx.y * 128;
  const int n0 = blockIdx.x * 128;
  const int t  = threadIdx.x;
  const int w    = t >> 6;
  const int lane = t & 63;
  const int quad = lane >> 4;
  const int l16  = lane & 15;
  const int m_off = (w >> 1) * 64;
  const int n_off = (w & 1) * 64;

  __shared__ unsigned short sm[17408];
  unsigned short* As = sm;
  unsigned short* Bs = sm + 8192;

  const int which = o0 >> 9;       // 0=Q,1=K,2=V
  const bool vmode = (which == 2);

  const int srow = lane >> 3;
  const int ssw  = ((lane & 7) ^ srow) * 8;
  const unsigned short* gA = wq + (size_t)(o0 + 32 * w + srow) * CC + ssw;
  const unsigned short* gB = xT + ((size_t)b * NN + n0 + 32 * w + srow) * CC + ssw;

  f32x4 acc[4][4] = {};

  for (int c0 = 0; c0 < CC; c0 += 64) {
    __syncthreads();
#pragma unroll
    for (int L = 0; L < 4; ++L) {
      gld_lds16(gA + (size_t)(8 * L) * CC + c0, &As[(32 * w + 8 * L) * 64]);
      gld_lds16(gB + (size_t)(8 * L) * CC + c0, &Bs[(32 * w + 8 * L) * 64]);
    }
    __syncthreads();
    const unsigned short* Af = vmode ? Bs : As;
    const unsigned short* Bf = vmode ? As : Bs;
#pragma unroll
    for (int ks = 0; ks < 2; ++ks) {
      const int ph = ((ks * 4 + quad) ^ (l16 & 7)) * 8;
      bf16x8 af[4], bfr[4];
#pragma unroll
      for (int i = 0; i < 4; ++i) {
        af[i]  = *(const bf16x8*)&Af[(m_off + 16 * i + l16) * 64 + ph];
        bfr[i] = *(const bf16x8*)&Bf[(n_off + 16 * i + l16) * 64 + ph];
      }
#pragma unroll
      for (int i = 0; i < 4; ++i)
#pragma unroll
        for (int j = 0; j < 4; ++j)
          acc[i][j] = __builtin_amdgcn_mfma_f32_16x16x32_bf16(af[i], bfr[j], acc[i][j], 0, 0, 0);
    }
  }

  __syncthreads();
  const float sc = (which == 0) ? QSCALE : 1.0f;
#pragma unroll
  for (int i = 0; i < 4; ++i) {
#pragma unroll
    for (int j = 0; j < 4; ++j) {
      const int Drow = m_off + 16 * i + quad * 4;
      const int Dcol = n_off + 16 * j + l16;
      ushort4 p;
      p.x = f2bf(acc[i][j][0] * sc);
      p.y = f2bf(acc[i][j][1] * sc);
      p.z = f2bf(acc[i][j][2] * sc);
      p.w = f2bf(acc[i][j][3] * sc);
      *(ushort4*)&sm[Dcol * 136 + Drow] = p;
    }
  }
  __syncthreads();
  const int lrow = t >> 1;
  const int half = t & 1;
  const unsigned short* src = &sm[lrow * 136 + 64 * half];
  if (!vmode) {
    const int hh = ((o0 >> 6) & 7) + half;
    unsigned short* dst = (which == 0 ? qb : kb_) +
        ((size_t)(b * NH + hh) * NN + n0 + lrow) * HD;
#pragma unroll
    for (int i = 0; i < 8; ++i) *(uint4*)(dst + 8 * i) = *(const uint4*)(src + 8 * i);
  } else {
    const int hh = ((o0 + lrow) >> 6) & 7;
    const int d  = lrow & 63;
    unsigned short* dst = vt + ((size_t)(b * NH + hh) * HD + d) * NN + n0 + 64 * half;
#pragma unroll
    for (int i = 0; i < 8; ++i) *(uint4*)(dst + 8 * i) = *(const uint4*)(src + 8 * i);
  }
}

// ---------------------------------------------------------------------------
// attn_mfma v10: v9 + FUSED kb SUB-BLOCKS for 4-way ILP.
// R6 findings: the 2.29M bank conflicts are gld_lds write serialization
// (reads were already slot-uniform; counter identical across swizzles) —
// closed. Issue-cycle accounting: all pipes sum to ~40% -> ~60% dependency
// stall at 2 waves/SIMD (occupancy is geometry-capped: 2048 waves total).
// v10 doubles intra-wave ILP: kb=0 and kb=1 (independent 32-key halves of
// each 64-key tile) are processed JOINTLY -> QK has 4 independent MFMA
// chains (stA0,stB0,stA1,stB1), SM has 128 independent exp2s, PV has 4
// independent accumulation chains. VGPR budget at 2 waves/SIMD is 256 —
// the extra ~100 live registers are free (no occupancy change possible).
// l-accumulators split 2->4 per query group to shorten serial add chains.
// ---------------------------------------------------------------------------
__global__ __launch_bounds__(256, 2) void attn_mfma(const unsigned short* __restrict__ Qg,
                                                    const unsigned short* __restrict__ Kg,
                                                    const unsigned short* __restrict__ Vtg,
                                                    unsigned short* __restrict__ attnB) {
  const int bh = blockIdx.x;     // id % 8 == bh % 8 -> XCD affinity
  const int b  = bh >> 3;
  const int h  = bh & 7;
  const int n0 = blockIdx.y * 256;
  const int t  = threadIdx.x;
  const int w    = t >> 6;
  const int lane = t & 63;
  const int l31  = lane & 31;
  const int hi   = lane >> 5;

  // K bufs: p*8192 + half*4096  (sm[0,16384))
  // V bufs: 16384 + p*8192 + half*4096  (sm[16384,32768))
  __shared__ unsigned short sm[32768];   // 64 KiB

  // two query groups per wave: A = n0 + w*64 + l31, B = A + 32
  const unsigned short* qrow = Qg + ((size_t)bh * NN + n0 + w * 64 + l31) * HD + hi * 8;
  bf16x8 qfA[4], qfB[4];
#pragma unroll
  for (int c = 0; c < 4; ++c) {
    qfA[c] = *(const bf16x8*)(qrow + 16 * c);
    qfB[c] = *(const bf16x8*)(qrow + 32 * HD + 16 * c);
  }

  // K A-row permutation: rho(l) swaps bits 2 and 3
  const int krow = (l31 & ~12) | ((l31 & 4) << 1) | ((l31 & 8) >> 1);
  const int ksw  = (krow >> 2) & 7;
  const int vsw  = (l31 >> 2) & 7;

  const f32x16 fz = {};
  f32x16 oaccA[2] = {}, oaccB[2] = {};   // O^T: D[m=d][n=query]
  float lA[4] = {}, lB[4] = {};          // 4 accum chains per query group

  // staging: wave w covers rows [16w,16w+16) of both K (keys) and V^T (d),
  // per 64-row half. Source col pre-swizzled with the (row>>2) involution.
  const int srow = lane >> 3;                     // 0..7
  const int sgA  = (lane & 7) ^ ((4 * w + (srow >> 2)) & 7);
  const int sgB  = (lane & 7) ^ ((4 * w + 2 + (srow >> 2)) & 7);
  const unsigned short* kstA = Kg + (size_t)bh * NN * HD +
                               (size_t)(16 * w + srow) * HD + sgA * 8;
  const unsigned short* kstB = Kg + (size_t)bh * NN * HD +
                               (size_t)(16 * w + 8 + srow) * HD + sgB * 8;
  const unsigned short* vstA = Vtg + (size_t)bh * HD * NN +
                               (size_t)(16 * w + srow) * NN + sgA * 8;
  const unsigned short* vstB = Vtg + (size_t)bh * HD * NN +
                               (size_t)(16 * w + 8 + srow) * NN + sgB * 8;
  const int kso0 = (16 * w) * 64;
  const int kso1 = (16 * w + 8) * 64;

  // stage one 128-key chunk (two 64-key halves) into buffer p
  auto stage = [&](int j0, int p) {
#pragma unroll
    for (int hf = 0; hf < 2; ++hf) {
      unsigned short* Kp = sm + p * 8192 + hf * 4096;
      unsigned short* Vp = sm + 16384 + p * 8192 + hf * 4096;
      const int jo = j0 + 64 * hf;
      gld_lds16(kstA + (size_t)jo * HD, Kp + kso0);
      gld_lds16(kstB + (size_t)jo * HD, Kp + kso1);
      gld_lds16(vstA + jo, Vp + kso0);
      gld_lds16(vstB + jo, Vp + kso1);
    }
  };

  // exp2 + l-accum (4 chains) + pack; P pairs ARE the PV B-fragment
  auto SM = [&](const f32x16& st, unsigned* P, float* l4) {
#pragma unroll
    for (int i = 0; i < 8; ++i) {
      float ea = EXP2F(st[2 * i]);
      float eb = EXP2F(st[2 * i + 1]);
      l4[2 * (i & 1)]     += ea;
      l4[2 * (i & 1) + 1] += eb;
      P[i] = pk2bf(ea, eb);
    }
  };

  // prologue: chunk 0 into buffer 0
  stage(0, 0);
  int cur = 0;

#pragma unroll 1
  for (int j0 = 0; j0 < NN; j0 += 128) {
    // implicit s_waitcnt vmcnt(0) here drains chunk-j0 loads (in flight for
    // a full 128-key compute phase), then publishes them to all waves.
    __syncthreads();
    if (j0 + 128 < NN) stage(j0 + 128, cur ^ 1);

#pragma unroll
    for (int hf = 0; hf < 2; ++hf) {
      const unsigned short* Ks = sm + cur * 8192 + hf * 4096;          // [key][d]
      const unsigned short* Vt = sm + 16384 + cur * 8192 + hf * 4096;  // [d][key]

      // ---- QK, both kb jointly: 4 independent MFMA chains ----
      const unsigned short* krp0 = &Ks[krow * 64];
      const unsigned short* krp1 = &Ks[(32 + krow) * 64];
      __builtin_amdgcn_s_setprio(1);
      f32x16 stA0, stB0, stA1, stB1;
      {
        bf16x8 k0 = *(const bf16x8*)(krp0 + (((0 + hi) ^ ksw) * 8));
        bf16x8 k1 = *(const bf16x8*)(krp1 + (((0 + hi) ^ ksw) * 8));
        stA0 = __builtin_amdgcn_mfma_f32_32x32x16_bf16(k0, qfA[0], fz, 0, 0, 0);
        stB0 = __builtin_amdgcn_mfma_f32_32x32x16_bf16(k0, qfB[0], fz, 0, 0, 0);
        stA1 = __builtin_amdgcn_mfma_f32_32x32x16_bf16(k1, qfA[0], fz, 0, 0, 0);
        stB1 = __builtin_amdgcn_mfma_f32_32x32x16_bf16(k1, qfB[0], fz, 0, 0, 0);
      }
#pragma unroll
      for (int c = 1; c < 4; ++c) {
        bf16x8 k0 = *(const bf16x8*)(krp0 + (((2 * c + hi) ^ ksw) * 8));
        bf16x8 k1 = *(const bf16x8*)(krp1 + (((2 * c + hi) ^ ksw) * 8));
        stA0 = __builtin_amdgcn_mfma_f32_32x32x16_bf16(k0, qfA[c], stA0, 0, 0, 0);
        stB0 = __builtin_amdgcn_mfma_f32_32x32x16_bf16(k0, qfB[c], stB0, 0, 0, 0);
        stA1 = __builtin_amdgcn_mfma_f32_32x32x16_bf16(k1, qfA[c], stA1, 0, 0, 0);
        stB1 = __builtin_amdgcn_mfma_f32_32x32x16_bf16(k1, qfB[c], stB1, 0, 0, 0);
      }
      __builtin_amdgcn_s_setprio(0);

      // ---- SM, 4 blocks: 128 independent exp2s ----
      unsigned PA0[8], PB0[8], PA1[8], PB1[8];
      SM(stA0, PA0, lA);
      SM(stB0, PB0, lB);
      SM(stA1, PA1, lA);
      SM(stB1, PB1, lB);

      // ---- PV, both kb jointly: 4 independent accumulation chains ----
      __builtin_amdgcn_s_setprio(1);
#pragma unroll
      for (int g = 0; g < 2; ++g) {
#pragma unroll
        for (int kb = 0; kb < 2; ++kb) {
          const unsigned* PA = kb ? PA1 : PA0;
          const unsigned* PB = kb ? PB1 : PB0;
          union { unsigned u[4]; bf16x8 v; } cvA, cvB;
          cvA.u[0] = PA[4 * g + 0]; cvA.u[1] = PA[4 * g + 1];
          cvA.u[2] = PA[4 * g + 2]; cvA.u[3] = PA[4 * g + 3];
          cvB.u[0] = PB[4 * g + 0]; cvB.u[1] = PB[4 * g + 1];
          cvB.u[2] = PB[4 * g + 2]; cvB.u[3] = PB[4 * g + 3];
#pragma unroll
          for (int mt = 0; mt < 2; ++mt) {
            const int vrow = 32 * mt + l31;
            bf16x8 vf = *(const bf16x8*)&Vt[vrow * 64 + (((4 * kb + 2 * g + hi) ^ vsw) * 8)];
            oaccA[mt] = __builtin_amdgcn_mfma_f32_32x32x16_bf16(vf, cvA.v, oaccA[mt], 0, 0, 0);
            oaccB[mt] = __builtin_amdgcn_mfma_f32_32x32x16_bf16(vf, cvB.v, oaccB[mt], 0, 0, 0);
          }
        }
      }
      __builtin_amdgcn_s_setprio(0);
    }
    cur ^= 1;
  }

  float lsA = (lA[0] + lA[1]) + (lA[2] + lA[3]);
  lsA += __shfl_xor(lsA, 32);
  const float invA = 1.0f / lsA;
  float lsB = (lB[0] + lB[1]) + (lB[2] + lB[3]);
  lsB += __shfl_xor(lsB, 32);
  const float invB = 1.0f / lsB;

  // epilogue: two wave-private passes through LDS [query][d] (pitch 72),
  // then 64B global writes. Barrier first: staging buffers overlap Es.
  __syncthreads();
  unsigned short* Es = sm + w * 2304;   // 32 * 72 shorts per wave
  const int q    = lane >> 1;
  const int half = lane & 1;
  const unsigned short* esrc = &Es[q * 72 + 32 * half];

  // ---- pass A ----
#pragma unroll
  for (int mt = 0; mt < 2; ++mt) {
#pragma unroll
    for (int rr = 0; rr < 4; ++rr) {
      const int d = 32 * mt + 8 * rr + 4 * hi;
      ushort4 p;
      p.x = f2bf(oaccA[mt][4 * rr + 0] * invA);
      p.y = f2bf(oaccA[mt][4 * rr + 1] * invA);
      p.z = f2bf(oaccA[mt][4 * rr + 2] * invA);
      p.w = f2bf(oaccA[mt][4 * rr + 3] * invA);
      *(ushort4*)&Es[l31 * 72 + d] = p;
    }
  }
  {
    unsigned short* gdst = attnB + ((size_t)b * NN + n0 + w * 64 + q) * CC + h * HD + 32 * half;
#pragma unroll
    for (int i = 0; i < 4; ++i) *(uint4*)(gdst + 8 * i) = *(const uint4*)(esrc + 8 * i);
  }

  // ---- pass B (same wave-private region; in-wave deps order LDS ops) ----
#pragma unroll
  for (int mt = 0; mt < 2; ++mt) {
#pragma unroll
    for (int rr = 0; rr < 4; ++rr) {
      const int d = 32 * mt + 8 * rr + 4 * hi;
      ushort4 p;
      p.x = f2bf(oaccB[mt][4 * rr + 0] * invB);
      p.y = f2bf(oaccB[mt][4 * rr + 1] * invB);
      p.z = f2bf(oaccB[mt][4 * rr + 2] * invB);
      p.w = f2bf(oaccB[mt][4 * rr + 3] * invB);
      *(ushort4*)&Es[l31 * 72 + d] = p;
    }
  }
  {
    unsigned short* gdst = attnB + ((size_t)b * NN + n0 + w * 64 + 32 + q) * CC + h * HD + 32 * half;
#pragma unroll
    for (int i = 0; i < 4; ++i) *(uint4*)(gdst + 8 * i) = *(const uint4*)(esrc + 8 * i);
  }
}

// ---------------------------------------------------------------------------
// proj_mfma: out = w_proj @ attn + bias, bf16 MFMA, fp32 out [b][c][n].
// ---------------------------------------------------------------------------
__global__ __launch_bounds__(256) void proj_mfma(const unsigned short* __restrict__ wp,
                                                 const unsigned short* __restrict__ aB,
                                                 const float* __restrict__ bias,
                                                 float* __restrict__ out) {
  const int b  = blockIdx.z;
  const int o0 = blockIdx.y * 128;
  const int n0 = blockIdx.x * 128;
  const int t  = threadIdx.x;
  const int w    = t >> 6;
  const int lane = t & 63;
  const int quad = lane >> 4;
  const int l16  = lane & 15;
  const int m_off = (w >> 1) * 64;
  const int n_off = (w & 1) * 64;

  __shared__ unsigned short sm[16384];
  unsigned short* As = sm;
  unsigned short* Bs = sm + 8192;

  const int srow = lane >> 3;
  const int ssw  = ((lane & 7) ^ srow) * 8;
  const unsigned short* gA = wp + (size_t)(o0 + 32 * w + srow) * CC + ssw;
  const unsigned short* gB = aB + ((size_t)b * NN + n0 + 32 * w + srow) * CC + ssw;

  f32x4 acc[4][4] = {};

  for (int c0 = 0; c0 < CC; c0 += 64) {
    __syncthreads();
#pragma unroll
    for (int L = 0; L < 4; ++L) {
      gld_lds16(gA + (size_t)(8 * L) * CC + c0, &As[(32 * w + 8 * L) * 64]);
      gld_lds16(gB + (size_t)(8 * L) * CC + c0, &Bs[(32 * w + 8 * L) * 64]);
    }
    __syncthreads();
#pragma unroll
    for (int ks = 0; ks < 2; ++ks) {
      const int ph = ((ks * 4 + quad) ^ (l16 & 7)) * 8;
      bf16x8 af[4], bfr[4];
#pragma unroll
      for (int i = 0; i < 4; ++i) {
        af[i]  = *(const bf16x8*)&As[(m_off + 16 * i + l16) * 64 + ph];
        bfr[i] = *(const bf16x8*)&Bs[(n_off + 16 * i + l16) * 64 + ph];
      }
#pragma unroll
      for (int i = 0; i < 4; ++i)
#pragma unroll
        for (int j = 0; j < 4; ++j)
          acc[i][j] = __builtin_amdgcn_mfma_f32_16x16x32_bf16(af[i], bfr[j], acc[i][j], 0, 0, 0);
    }
  }

#pragma unroll
  for (int i = 0; i < 4; ++i) {
#pragma unroll
    for (int r = 0; r < 4; ++r) {
      const int o = o0 + m_off + 16 * i + quad * 4 + r;
      const float bv = bias[o];
      float* orow = out + ((size_t)b * CC + o) * NN + n0 + n_off;
#pragma unroll
      for (int j = 0; j < 4; ++j)
        orow[16 * j + l16] = acc[i][j][r] + bv;
    }
  }
}

// ---------------------------------------------------------------------------
extern "C" void kernel_launch(void* const* d_in, const int* in_sizes, int n_in,
                              void* d_out, int out_size, void* d_ws, size_t ws_size,
                              hipStream_t stream) {
  const float* x      = (const float*)d_in[0];
  const float* w_qkv  = (const float*)d_in[1];
  const float* w_proj = (const float*)d_in[2];
  const float* b_proj = (const float*)d_in[3];
  char* wsb  = (char*)d_ws;
  float* out = (float*)d_out;

  unsigned short* xT  = (unsigned short*)(wsb + XT_OFF);
  unsigned short* wq  = (unsigned short*)(wsb + WQ_OFF);
  unsigned short* wp  = (unsigned short*)(wsb + WP_OFF);
  unsigned short* qb  = (unsigned short*)(wsb + QB_OFF);
  unsigned short* kb_ = (unsigned short*)(wsb + KB_OFF);
  unsigned short* vt  = (unsigned short*)(wsb + VT_OFF);
  unsigned short* aB  = (unsigned short*)(wsb + AB_OFF);

  prep_w<<<512, 256, 0, stream>>>(w_qkv, w_proj, wq, wp);
  prep_xT<<<dim3(16, 8, BB), 256, 0, stream>>>(x, xT);
  qkv_mfma<<<dim3(8, 12, BB), 256, 0, stream>>>(wq, xT, qb, kb_, vt);
  attn_mfma<<<dim3(BB * NH, NN / 256), 256, 0, stream>>>(qb, kb_, vt, aB);
  proj_mfma<<<dim3(8, 4, BB), 256, 0, stream>>>(wp, aB, b_proj, out);
}

// Round 8
// 184.593 us; speedup vs baseline: 1.0487x; 1.0487x over previous
//
#include <hip/hip_runtime.h>
#include <hip/hip_bf16.h>
#include <math.h>

#define BB 16
#define CC 512
#define NH 8
#define HD 64
#define NN 1024   // H*W
#define THREEC 1536

// Q pre-scale: (1/sqrt(64)) * log2(e)  -> softmax via raw v_exp_f32 (2^x)
#define QSCALE 0.18033688f

typedef __attribute__((ext_vector_type(8))) short bf16x8;
typedef __attribute__((ext_vector_type(4))) float f32x4;
typedef __attribute__((ext_vector_type(16))) float f32x16;

#if __has_builtin(__builtin_amdgcn_exp2f)
#define EXP2F __builtin_amdgcn_exp2f
#else
#define EXP2F exp2f
#endif

// workspace byte offsets
#define XT_OFF 0u           // bf16 x^T [b][n][c]          (16.78 MB)
#define WQ_OFF 16777216u    // bf16 w_qkv [1536][512]      (1.57 MB)
#define WP_OFF 18350080u    // bf16 w_proj [512][512]      (0.52 MB)
#define QB_OFF 18874368u    // bf16 Q (scaled QSCALE) [bh][n][d]
#define KB_OFF 35651584u    // bf16 K [bh][n][d]
#define VT_OFF 52428800u    // bf16 V^T [bh][d][n]
#define AB_OFF 69206016u    // bf16 attn-out [b][n][c]
// end 85983232 (82 MiB)

static __device__ inline unsigned short f2bf(float f) {
  union { float f; unsigned u; } v; v.f = f;
  unsigned r = v.u + 0x7fffu + ((v.u >> 16) & 1u);
  return (unsigned short)(r >> 16);
}

// pack two f32 -> two bf16 in a u32 (lo = a, hi = b)
static __device__ inline unsigned pk2bf(float a, float b) {
#if defined(__AMDGCN__) && __has_builtin(__builtin_amdgcn_cvt_pk_bf16_f32)
  typedef __attribute__((ext_vector_type(2))) __bf16 bfp2;
  union { bfp2 v; unsigned u; } z;
  z.v = __builtin_amdgcn_cvt_pk_bf16_f32(a, b);
  return z.u;
#else
  return (unsigned)f2bf(a) | ((unsigned)f2bf(b) << 16);
#endif
}

static __device__ inline void gld_lds16(const unsigned short* g, unsigned short* l) {
  __builtin_amdgcn_global_load_lds(
      (const __attribute__((address_space(1))) unsigned int*)g,
      (__attribute__((address_space(3))) unsigned int*)l, 16, 0, 0);
}

// ---------------------------------------------------------------------------
// prep_fused: x [b][c][n] fp32 -> xT [b][n][c] bf16 (64x64 LDS transpose),
// PLUS (first 512 blocks) w_qkv/w_proj fp32 -> bf16 conversion folded in —
// saves one kernel launch; the extra ~6 MB of weight traffic is spread over
// 512 of 2048 blocks (tail-free vs the 50 MB xT workload).
// ---------------------------------------------------------------------------
__global__ __launch_bounds__(256) void prep_fused(const float* __restrict__ x,
                                                  unsigned short* __restrict__ xT,
                                                  const float* __restrict__ wqkv,
                                                  const float* __restrict__ wproj,
                                                  unsigned short* __restrict__ dq,
                                                  unsigned short* __restrict__ dp) {
  const int b  = blockIdx.z;
  const int c0 = blockIdx.y * 64;
  const int n0 = blockIdx.x * 64;
  __shared__ float tile[64][65];
  const int t  = threadIdx.x;

  // ---- folded prep_w: blocks with z<4 form wid 0..511 ----
  const int wid = (blockIdx.z * 8 + blockIdx.y) * 16 + blockIdx.x;
  if (wid < 512) {
    const size_t i8 = ((size_t)wid * 256 + t) * 8;
    const float* src;
    unsigned short* dst;
    if (i8 < 786432u) { src = wqkv + i8; dst = dq + i8; }
    else              { src = wproj + (i8 - 786432u); dst = dp + (i8 - 786432u); }
    float4 a = *(const float4*)src;
    float4 b4 = *(const float4*)(src + 4);
    unsigned short pk[8] = {f2bf(a.x), f2bf(a.y), f2bf(a.z), f2bf(a.w),
                            f2bf(b4.x), f2bf(b4.y), f2bf(b4.z), f2bf(b4.w)};
    *(uint4*)dst = *(const uint4*)pk;
  }

  // ---- xT transpose ----
  const int cl = t >> 4, n4 = (t & 15) * 4;
#pragma unroll
  for (int r = 0; r < 4; ++r) {
    float4 v = *(const float4*)&x[((size_t)b * CC + c0 + cl + 16 * r) * NN + n0 + n4];
    *(float4*)&tile[cl + 16 * r][n4] = v;
  }
  __syncthreads();
  const int nl = t >> 4, c4 = (t & 15) * 4;
#pragma unroll
  for (int r = 0; r < 4; ++r) {
    ushort4 p;
    p.x = f2bf(tile[c4 + 0][nl + 16 * r]);
    p.y = f2bf(tile[c4 + 1][nl + 16 * r]);
    p.z = f2bf(tile[c4 + 2][nl + 16 * r]);
    p.w = f2bf(tile[c4 + 3][nl + 16 * r]);
    *(ushort4*)&xT[((size_t)b * NN + n0 + nl + 16 * r) * CC + c0 + c4] = p;
  }
}

// ---------------------------------------------------------------------------
// qkv_mfma: [1536x512] @ [512x1024] per batch, bf16 MFMA, 128x128 tile BK=64.
// ---------------------------------------------------------------------------
__global__ __launch_bounds__(256) void qkv_mfma(const unsigned short* __restrict__ wq,
                                                const unsigned short* __restrict__ xT,
                                                unsigned short* __restrict__ qb,
                                                unsigned short* __restrict__ kb_,
                                                unsigned short* __restrict__ vt) {
  const int b  = blockIdx.z;
  const int o0 = blockIdx.y * 128;
  const int n0 = blockIdx.x * 128;
  const int t  = threadIdx.x;
  const int w    = t >> 6;
  const int lane = t & 63;
  const int quad = lane >> 4;
  const int l16  = lane & 15;
  const int m_off = (w >> 1) * 64;
  const int n_off = (w & 1) * 64;

  __shared__ unsigned short sm[17408];
  unsigned short* As = sm;
  unsigned short* Bs = sm + 8192;

  const int which = o0 >> 9;       // 0=Q,1=K,2=V
  const bool vmode = (which == 2);

  const int srow = lane >> 3;
  const int ssw  = ((lane & 7) ^ srow) * 8;
  const unsigned short* gA = wq + (size_t)(o0 + 32 * w + srow) * CC + ssw;
  const unsigned short* gB = xT + ((size_t)b * NN + n0 + 32 * w + srow) * CC + ssw;

  f32x4 acc[4][4] = {};

  for (int c0 = 0; c0 < CC; c0 += 64) {
    __syncthreads();
#pragma unroll
    for (int L = 0; L < 4; ++L) {
      gld_lds16(gA + (size_t)(8 * L) * CC + c0, &As[(32 * w + 8 * L) * 64]);
      gld_lds16(gB + (size_t)(8 * L) * CC + c0, &Bs[(32 * w + 8 * L) * 64]);
    }
    __syncthreads();
    const unsigned short* Af = vmode ? Bs : As;
    const unsigned short* Bf = vmode ? As : Bs;
#pragma unroll
    for (int ks = 0; ks < 2; ++ks) {
      const int ph = ((ks * 4 + quad) ^ (l16 & 7)) * 8;
      bf16x8 af[4], bfr[4];
#pragma unroll
      for (int i = 0; i < 4; ++i) {
        af[i]  = *(const bf16x8*)&Af[(m_off + 16 * i + l16) * 64 + ph];
        bfr[i] = *(const bf16x8*)&Bf[(n_off + 16 * i + l16) * 64 + ph];
      }
#pragma unroll
      for (int i = 0; i < 4; ++i)
#pragma unroll
        for (int j = 0; j < 4; ++j)
          acc[i][j] = __builtin_amdgcn_mfma_f32_16x16x32_bf16(af[i], bfr[j], acc[i][j], 0, 0, 0);
    }
  }

  __syncthreads();
  const float sc = (which == 0) ? QSCALE : 1.0f;
#pragma unroll
  for (int i = 0; i < 4; ++i) {
#pragma unroll
    for (int j = 0; j < 4; ++j) {
      const int Drow = m_off + 16 * i + quad * 4;
      const int Dcol = n_off + 16 * j + l16;
      ushort4 p;
      p.x = f2bf(acc[i][j][0] * sc);
      p.y = f2bf(acc[i][j][1] * sc);
      p.z = f2bf(acc[i][j][2] * sc);
      p.w = f2bf(acc[i][j][3] * sc);
      *(ushort4*)&sm[Dcol * 136 + Drow] = p;
    }
  }
  __syncthreads();
  const int lrow = t >> 1;
  const int half = t & 1;
  const unsigned short* src = &sm[lrow * 136 + 64 * half];
  if (!vmode) {
    const int hh = ((o0 >> 6) & 7) + half;
    unsigned short* dst = (which == 0 ? qb : kb_) +
        ((size_t)(b * NH + hh) * NN + n0 + lrow) * HD;
#pragma unroll
    for (int i = 0; i < 8; ++i) *(uint4*)(dst + 8 * i) = *(const uint4*)(src + 8 * i);
  } else {
    const int hh = ((o0 + lrow) >> 6) & 7;
    const int d  = lrow & 63;
    unsigned short* dst = vt + ((size_t)(b * NH + hh) * HD + d) * NN + n0 + 64 * half;
#pragma unroll
    for (int i = 0; i < 8; ++i) *(uint4*)(dst + 8 * i) = *(const uint4*)(src + 8 * i);
  }
}

// ---------------------------------------------------------------------------
// attn_mfma v9 (PROVEN BEST: 47.7us): v8 64 q/wave + chunk=128 dbuf.
// v10's fused-kb 4-way ILP regressed (compiler re-serialized at VGPR 124,
// FETCH +3.5MB) — reverted. Per-CU accounting at this structure: LDS-pipe
// ~45%, VALU/trans ~35%, 2 waves/SIMD geometry-capped -> plateau.
// ---------------------------------------------------------------------------
__global__ __launch_bounds__(256, 2) void attn_mfma(const unsigned short* __restrict__ Qg,
                                                    const unsigned short* __restrict__ Kg,
                                                    const unsigned short* __restrict__ Vtg,
                                                    unsigned short* __restrict__ attnB) {
  const int bh = blockIdx.x;     // id % 8 == bh % 8 -> XCD affinity
  const int b  = bh >> 3;
  const int h  = bh & 7;
  const int n0 = blockIdx.y * 256;
  const int t  = threadIdx.x;
  const int w    = t >> 6;
  const int lane = t & 63;
  const int l31  = lane & 31;
  const int hi   = lane >> 5;

  // K bufs: p*8192 + half*4096  (sm[0,16384))
  // V bufs: 16384 + p*8192 + half*4096  (sm[16384,32768))
  __shared__ unsigned short sm[32768];   // 64 KiB

  // two query groups per wave: A = n0 + w*64 + l31, B = A + 32
  const unsigned short* qrow = Qg + ((size_t)bh * NN + n0 + w * 64 + l31) * HD + hi * 8;
  bf16x8 qfA[4], qfB[4];
#pragma unroll
  for (int c = 0; c < 4; ++c) {
    qfA[c] = *(const bf16x8*)(qrow + 16 * c);
    qfB[c] = *(const bf16x8*)(qrow + 32 * HD + 16 * c);
  }

  // K A-row permutation: rho(l) swaps bits 2 and 3
  const int krow = (l31 & ~12) | ((l31 & 4) << 1) | ((l31 & 8) >> 1);
  const int ksw  = (krow >> 2) & 7;
  const int vsw  = (l31 >> 2) & 7;

  const f32x16 fz = {};
  f32x16 oaccA[2] = {}, oaccB[2] = {};   // O^T: D[m=d][n=query]
  float lxA = 0.f, lyA = 0.f, lxB = 0.f, lyB = 0.f;

  // staging: wave w covers rows [16w,16w+16) of both K (keys) and V^T (d),
  // per 64-row half. Source col pre-swizzled with the (row>>2) involution.
  const int srow = lane >> 3;                     // 0..7
  const int sgA  = (lane & 7) ^ ((4 * w + (srow >> 2)) & 7);
  const int sgB  = (lane & 7) ^ ((4 * w + 2 + (srow >> 2)) & 7);
  const unsigned short* kstA = Kg + (size_t)bh * NN * HD +
                               (size_t)(16 * w + srow) * HD + sgA * 8;
  const unsigned short* kstB = Kg + (size_t)bh * NN * HD +
                               (size_t)(16 * w + 8 + srow) * HD + sgB * 8;
  const unsigned short* vstA = Vtg + (size_t)bh * HD * NN +
                               (size_t)(16 * w + srow) * NN + sgA * 8;
  const unsigned short* vstB = Vtg + (size_t)bh * HD * NN +
                               (size_t)(16 * w + 8 + srow) * NN + sgB * 8;
  const int kso0 = (16 * w) * 64;
  const int kso1 = (16 * w + 8) * 64;

  // stage one 128-key chunk (two 64-key halves) into buffer p
  auto stage = [&](int j0, int p) {
#pragma unroll
    for (int hf = 0; hf < 2; ++hf) {
      unsigned short* Kp = sm + p * 8192 + hf * 4096;
      unsigned short* Vp = sm + 16384 + p * 8192 + hf * 4096;
      const int jo = j0 + 64 * hf;
      gld_lds16(kstA + (size_t)jo * HD, Kp + kso0);
      gld_lds16(kstB + (size_t)jo * HD, Kp + kso1);
      gld_lds16(vstA + jo, Vp + kso0);
      gld_lds16(vstB + jo, Vp + kso1);
    }
  };

  // prologue: chunk 0 into buffer 0
  stage(0, 0);
  int cur = 0;

#pragma unroll 1
  for (int j0 = 0; j0 < NN; j0 += 128) {
    // implicit s_waitcnt vmcnt(0) here drains chunk-j0 loads (in flight for
    // a full 128-key compute phase), then publishes them to all waves.
    __syncthreads();
    if (j0 + 128 < NN) stage(j0 + 128, cur ^ 1);

#pragma unroll
    for (int hf = 0; hf < 2; ++hf) {
      const unsigned short* Ks = sm + cur * 8192 + hf * 4096;          // [key][d]
      const unsigned short* Vt = sm + 16384 + cur * 8192 + hf * 4096;  // [d][key]

#pragma unroll
      for (int kb = 0; kb < 2; ++kb) {
        // S^T: A[m]=K row rho(m) (32 keys), B=Q; contract over d.
        // kf read ONCE from LDS, feeds both query groups.
        const unsigned short* krp = &Ks[(32 * kb + krow) * 64];
        __builtin_amdgcn_s_setprio(1);
        bf16x8 kf0 = *(const bf16x8*)(krp + (((0 + hi) ^ ksw) * 8));
        f32x16 stA = __builtin_amdgcn_mfma_f32_32x32x16_bf16(kf0, qfA[0], fz, 0, 0, 0);
        f32x16 stB = __builtin_amdgcn_mfma_f32_32x32x16_bf16(kf0, qfB[0], fz, 0, 0, 0);
#pragma unroll
        for (int c = 1; c < 4; ++c) {
          bf16x8 kf = *(const bf16x8*)(krp + (((2 * c + hi) ^ ksw) * 8));
          stA = __builtin_amdgcn_mfma_f32_32x32x16_bf16(kf, qfA[c], stA, 0, 0, 0);
          stB = __builtin_amdgcn_mfma_f32_32x32x16_bf16(kf, qfB[c], stB, 0, 0, 0);
        }
        __builtin_amdgcn_s_setprio(0);
        // exp2 (Q carries log2e/8) + l accum + pack; P pairs ARE the PV
        // B-fragment (key permutation absorbed rho)
        unsigned PA[8], PB[8];
#pragma unroll
        for (int i = 0; i < 8; ++i) {
          float ea = EXP2F(stA[2 * i]);
          float eb = EXP2F(stA[2 * i + 1]);
          lxA += ea; lyA += eb;
          PA[i] = pk2bf(ea, eb);
        }
#pragma unroll
        for (int i = 0; i < 8; ++i) {
          float ea = EXP2F(stB[2 * i]);
          float eb = EXP2F(stB[2 * i + 1]);
          lxB += ea; lyB += eb;
          PB[i] = pk2bf(ea, eb);
        }

        __builtin_amdgcn_s_setprio(1);
#pragma unroll
        for (int g = 0; g < 2; ++g) {
          union { unsigned u[4]; bf16x8 v; } cvA, cvB;
          cvA.u[0] = PA[4 * g + 0]; cvA.u[1] = PA[4 * g + 1];
          cvA.u[2] = PA[4 * g + 2]; cvA.u[3] = PA[4 * g + 3];
          cvB.u[0] = PB[4 * g + 0]; cvB.u[1] = PB[4 * g + 1];
          cvB.u[2] = PB[4 * g + 2]; cvB.u[3] = PB[4 * g + 3];
#pragma unroll
          for (int mt = 0; mt < 2; ++mt) {
            const int vrow = 32 * mt + l31;
            // vf read ONCE from LDS, feeds both query groups.
            bf16x8 vf = *(const bf16x8*)&Vt[vrow * 64 + (((4 * kb + 2 * g + hi) ^ vsw) * 8)];
            oaccA[mt] = __builtin_amdgcn_mfma_f32_32x32x16_bf16(vf, cvA.v, oaccA[mt], 0, 0, 0);
            oaccB[mt] = __builtin_amdgcn_mfma_f32_32x32x16_bf16(vf, cvB.v, oaccB[mt], 0, 0, 0);
          }
        }
        __builtin_amdgcn_s_setprio(0);
      }
    }
    cur ^= 1;
  }

  float lsA = lxA + lyA;
  lsA += __shfl_xor(lsA, 32);
  const float invA = 1.0f / lsA;
  float lsB = lxB + lyB;
  lsB += __shfl_xor(lsB, 32);
  const float invB = 1.0f / lsB;

  // epilogue: two wave-private passes through LDS [query][d] (pitch 72),
  // then 64B global writes. Barrier first: staging buffers overlap Es.
  __syncthreads();
  unsigned short* Es = sm + w * 2304;   // 32 * 72 shorts per wave
  const int q    = lane >> 1;
  const int half = lane & 1;
  const unsigned short* esrc = &Es[q * 72 + 32 * half];

  // ---- pass A ----
#pragma unroll
  for (int mt = 0; mt < 2; ++mt) {
#pragma unroll
    for (int rr = 0; rr < 4; ++rr) {
      const int d = 32 * mt + 8 * rr + 4 * hi;
      ushort4 p;
      p.x = f2bf(oaccA[mt][4 * rr + 0] * invA);
      p.y = f2bf(oaccA[mt][4 * rr + 1] * invA);
      p.z = f2bf(oaccA[mt][4 * rr + 2] * invA);
      p.w = f2bf(oaccA[mt][4 * rr + 3] * invA);
      *(ushort4*)&Es[l31 * 72 + d] = p;
    }
  }
  {
    unsigned short* gdst = attnB + ((size_t)b * NN + n0 + w * 64 + q) * CC + h * HD + 32 * half;
#pragma unroll
    for (int i = 0; i < 4; ++i) *(uint4*)(gdst + 8 * i) = *(const uint4*)(esrc + 8 * i);
  }

  // ---- pass B (same wave-private region; in-wave deps order LDS ops) ----
#pragma unroll
  for (int mt = 0; mt < 2; ++mt) {
#pragma unroll
    for (int rr = 0; rr < 4; ++rr) {
      const int d = 32 * mt + 8 * rr + 4 * hi;
      ushort4 p;
      p.x = f2bf(oaccB[mt][4 * rr + 0] * invB);
      p.y = f2bf(oaccB[mt][4 * rr + 1] * invB);
      p.z = f2bf(oaccB[mt][4 * rr + 2] * invB);
      p.w = f2bf(oaccB[mt][4 * rr + 3] * invB);
      *(ushort4*)&Es[l31 * 72 + d] = p;
    }
  }
  {
    unsigned short* gdst = attnB + ((size_t)b * NN + n0 + w * 64 + 32 + q) * CC + h * HD + 32 * half;
#pragma unroll
    for (int i = 0; i < 4; ++i) *(uint4*)(gdst + 8 * i) = *(const uint4*)(esrc + 8 * i);
  }
}

// ---------------------------------------------------------------------------
// proj_mfma: out = w_proj @ attn + bias, bf16 MFMA, fp32 out [b][c][n].
// ---------------------------------------------------------------------------
__global__ __launch_bounds__(256) void proj_mfma(const unsigned short* __restrict__ wp,
                                                 const unsigned short* __restrict__ aB,
                                                 const float* __restrict__ bias,
                                                 float* __restrict__ out) {
  const int b  = blockIdx.z;
  const int o0 = blockIdx.y * 128;
  const int n0 = blockIdx.x * 128;
  const int t  = threadIdx.x;
  const int w    = t >> 6;
  const int lane = t & 63;
  const int quad = lane >> 4;
  const int l16  = lane & 15;
  const int m_off = (w >> 1) * 64;
  const int n_off = (w & 1) * 64;

  __shared__ unsigned short sm[16384];
  unsigned short* As = sm;
  unsigned short* Bs = sm + 8192;

  const int srow = lane >> 3;
  const int ssw  = ((lane & 7) ^ srow) * 8;
  const unsigned short* gA = wp + (size_t)(o0 + 32 * w + srow) * CC + ssw;
  const unsigned short* gB = aB + ((size_t)b * NN + n0 + 32 * w + srow) * CC + ssw;

  f32x4 acc[4][4] = {};

  for (int c0 = 0; c0 < CC; c0 += 64) {
    __syncthreads();
#pragma unroll
    for (int L = 0; L < 4; ++L) {
      gld_lds16(gA + (size_t)(8 * L) * CC + c0, &As[(32 * w + 8 * L) * 64]);
      gld_lds16(gB + (size_t)(8 * L) * CC + c0, &Bs[(32 * w + 8 * L) * 64]);
    }
    __syncthreads();
#pragma unroll
    for (int ks = 0; ks < 2; ++ks) {
      const int ph = ((ks * 4 + quad) ^ (l16 & 7)) * 8;
      bf16x8 af[4], bfr[4];
#pragma unroll
      for (int i = 0; i < 4; ++i) {
        af[i]  = *(const bf16x8*)&As[(m_off + 16 * i + l16) * 64 + ph];
        bfr[i] = *(const bf16x8*)&Bs[(n_off + 16 * i + l16) * 64 + ph];
      }
#pragma unroll
      for (int i = 0; i < 4; ++i)
#pragma unroll
        for (int j = 0; j < 4; ++j)
          acc[i][j] = __builtin_amdgcn_mfma_f32_16x16x32_bf16(af[i], bfr[j], acc[i][j], 0, 0, 0);
    }
  }

#pragma unroll
  for (int i = 0; i < 4; ++i) {
#pragma unroll
    for (int r = 0; r < 4; ++r) {
      const int o = o0 + m_off + 16 * i + quad * 4 + r;
      const float bv = bias[o];
      float* orow = out + ((size_t)b * CC + o) * NN + n0 + n_off;
#pragma unroll
      for (int j = 0; j < 4; ++j)
        orow[16 * j + l16] = acc[i][j][r] + bv;
    }
  }
}

// ---------------------------------------------------------------------------
extern "C" void kernel_launch(void* const* d_in, const int* in_sizes, int n_in,
                              void* d_out, int out_size, void* d_ws, size_t ws_size,
                              hipStream_t stream) {
  const float* x      = (const float*)d_in[0];
  const float* w_qkv  = (const float*)d_in[1];
  const float* w_proj = (const float*)d_in[2];
  const float* b_proj = (const float*)d_in[3];
  char* wsb  = (char*)d_ws;
  float* out = (float*)d_out;

  unsigned short* xT  = (unsigned short*)(wsb + XT_OFF);
  unsigned short* wq  = (unsigned short*)(wsb + WQ_OFF);
  unsigned short* wp  = (unsigned short*)(wsb + WP_OFF);
  unsigned short* qb  = (unsigned short*)(wsb + QB_OFF);
  unsigned short* kb_ = (unsigned short*)(wsb + KB_OFF);
  unsigned short* vt  = (unsigned short*)(wsb + VT_OFF);
  unsigned short* aB  = (unsigned short*)(wsb + AB_OFF);

  prep_fused<<<dim3(16, 8, BB), 256, 0, stream>>>(x, xT, w_qkv, w_proj, wq, wp);
  qkv_mfma<<<dim3(8, 12, BB), 256, 0, stream>>>(wq, xT, qb, kb_, vt);
  attn_mfma<<<dim3(BB * NH, NN / 256), 256, 0, stream>>>(qb, kb_, vt, aB);
  proj_mfma<<<dim3(8, 4, BB), 256, 0, stream>>>(wp, aB, b_proj, out);
}